// Round 4
// baseline (641.144 us; speedup 1.0000x reference)
//
#include <hip/hip_runtime.h>
#include <math.h>

// EdgeEmbeddingBlock: out_r[e,k,n,j] = radial[e,n] * na[sender[e],k] * ylm_r[e,j]
//                     out_i[e,k,n,j] = radial[e,n] * na[sender[e],k] * ylm_i[e,j]
// Constants: E=60000, N_NODES=4000, K_ATTR=10, NMAX=8, J=16 (LMAX=3),
// R_CUT=5, P_CUT=6.
//
// ALL I/O IS FLOAT32 (reference dtypes; edge_index int32). Round 1-3
// post-mortem: bf16 assumption was wrong — reading f32 as bf16 gave NaN
// (round 1); writing bf16 into an f32-checked buffer gave err≈max|ref|
// (rounds 2/3, bit-identical 5.625113).
//
// Output = 2 * 60000*10*8*16 f32 = 614.4 MB -> write-BW bound (~98 us floor).
//
// Mapping: one wave per edge. Per-edge r/i each = 1280 f32 = 320 chunks of
// 4 f32 (16 B). chunk c = lane + 64*it = k*32 + n*4 + jq with
// jq=lane&3, n=(lane>>2)&7, kh=lane>>5 (all lane-fixed), k=kh+2*it, it=0..4
// -> covers k in [0,10) exactly. Two dwordx4 stores per lane per iter.

#define E_CONST 60000
#define N_NODES 4000
#define K_ATTR 10
#define PER_EDGE 1280  // K_ATTR*8*16

__global__ __launch_bounds__(256) void edge_embed_kernel(
    const int* __restrict__ edge_index,
    const float* __restrict__ lengths,
    const float* __restrict__ vecs,
    const float* __restrict__ attrs,
    float* __restrict__ out)
{
    const int wid = (blockIdx.x * blockDim.x + threadIdx.x) >> 6;
    if (wid >= E_CONST) return;
    const int lane = threadIdx.x & 63;
    const int e = wid;

    // ---- per-edge loads (wave-uniform addresses -> broadcast) ----
    const float x  = lengths[e];
    const float vx = vecs[3*e + 0];
    const float vy = vecs[3*e + 1];
    const float vz = vecs[3*e + 2];
    int sender = edge_index[e];                 // row 0 of (2,E), int32
    sender = min(max(sender, 0), N_NODES - 1);  // safety clamp

    // ---- lane's fixed (jq, n, kh) ----
    const int jq = lane & 3;         // j-quad: j = 4*jq .. 4*jq+3
    const int n  = (lane >> 2) & 7;  // radial index
    const int kh = lane >> 5;        // k = kh + 2*it

    // ---- radial for this lane's n ----
    const float u  = x * 0.2f;                                // x / R_CUT
    const float u2 = u * u, u3 = u2 * u;
    const float u6 = u3 * u3, u7 = u6 * u, u8 = u7 * u;
    float env = 1.0f - 28.0f * u6 + 48.0f * u7 - 21.0f * u8;  // p=6 poly cutoff
    env = (u < 1.0f) ? env : 0.0f;
    const float PREF = 0.63245553203367586f;                  // sqrt(2/5)
    const float w = (float)(n + 1) * 0.6283185307179586f;     // (n+1)*pi/5
    const float rad = PREF * sinf(w * x) / x * env;

    // ---- unit direction ----
    const float nrm = sqrtf(vx*vx + vy*vy + vz*vz);
    const float inv = 1.0f / fmaxf(nrm, 1e-9f);
    const float ux = vx * inv, uy = vy * inv, uz = vz * inv;
    const float z = uz, z2 = z * z;

    // c_m = st^m cos(m phi), s_m = st^m sin(m phi); st*cosphi=ux, st*sinphi=uy
    const float c1 = ux,            s1 = uy;
    const float c2 = c1*ux - s1*uy, s2 = s1*ux + c1*uy;
    const float c3 = c2*ux - s2*uy, s3 = s2*ux + c2*uy;

    // Q[l,m] = P[l,m]/st^m (polynomials in z)
    const float Q10 = z;
    const float Q20 = 1.5f*z2 - 0.5f;
    const float Q21 = -3.0f*z;
    const float Q30 = (2.5f*z2 - 1.5f)*z;
    const float Q31 = 1.5f - 7.5f*z2;
    const float Q32 = 15.0f*z;

    // normalization nlm = sqrt((2l+1)/(4pi) * (l-|m|)!/(l+|m|)!)
    const float n00 = 0.28209479177387814f;
    const float n10 = 0.4886025119029199f,  n11 = 0.34549414947133544f;
    const float n20 = 0.6307831305050401f,  n21 = 0.2575161346821595f,  n22 = 0.12875806798063624f;
    const float n30 = 0.7463526651802308f,  n31 = 0.2154534560075959f,  n32 = 0.06813236509555449f, n33 = 0.027814921575518937f;

    // base(l,|m|): br = nlm*Q*c_m, bi = nlm*Q*s_m  (|m| >= 1)
    const float b1r  = n11 * (-1.0f) * c1, b1i  = n11 * (-1.0f) * s1;
    const float b21r = n21 * Q21 * c1,     b21i = n21 * Q21 * s1;
    const float b22r = n22 * 3.0f * c2,    b22i = n22 * 3.0f * s2;
    const float b31r = n31 * Q31 * c1,     b31i = n31 * Q31 * s1;
    const float b32r = n32 * Q32 * c2,     b32i = n32 * Q32 * s2;
    const float b33r = n33 * (-15.0f)*c3,  b33i = n33 * (-15.0f)*s3;

    // j ordering: l=0..3, m=-l..l.  m<0: s=(-1)^|m|, re=s*br, im=-s*bi.
    float yr[16], yi[16];
    yr[0]  =  n00;        yi[0]  =  0.0f;
    yr[1]  = -b1r;        yi[1]  =  b1i;    // (1,-1)
    yr[2]  =  n10 * Q10;  yi[2]  =  0.0f;   // (1, 0)
    yr[3]  =  b1r;        yi[3]  =  b1i;    // (1, 1)
    yr[4]  =  b22r;       yi[4]  = -b22i;   // (2,-2)
    yr[5]  = -b21r;       yi[5]  =  b21i;   // (2,-1)
    yr[6]  =  n20 * Q20;  yi[6]  =  0.0f;   // (2, 0)
    yr[7]  =  b21r;       yi[7]  =  b21i;   // (2, 1)
    yr[8]  =  b22r;       yi[8]  =  b22i;   // (2, 2)
    yr[9]  = -b33r;       yi[9]  =  b33i;   // (3,-3)
    yr[10] =  b32r;       yi[10] = -b32i;   // (3,-2)
    yr[11] = -b31r;       yi[11] =  b31i;   // (3,-1)
    yr[12] =  n30 * Q30;  yi[12] =  0.0f;   // (3, 0)
    yr[13] =  b31r;       yi[13] =  b31i;   // (3, 1)
    yr[14] =  b32r;       yi[14] =  b32i;   // (3, 2)
    yr[15] =  b33r;       yi[15] =  b33i;   // (3, 3)

    // select this lane's j-quad (jq loop-invariant -> cndmask tree)
    float ysr[4], ysi[4];
#pragma unroll
    for (int t = 0; t < 4; ++t) {
        const float r01 = (jq & 1) ? yr[4 + t]  : yr[t];
        const float r23 = (jq & 1) ? yr[12 + t] : yr[8 + t];
        const float i01 = (jq & 1) ? yi[4 + t]  : yi[t];
        const float i23 = (jq & 1) ? yi[12 + t] : yi[8 + t];
        ysr[t] = (jq & 2) ? r23 : r01;
        ysi[t] = (jq & 2) ? i23 : i01;
    }

    const size_t base_r = (size_t)e * PER_EDGE;
    const size_t base_i = (size_t)E_CONST * PER_EDGE + base_r;

#pragma unroll
    for (int it = 0; it < 5; ++it) {
        const int k = kh + 2 * it;                 // covers 0..9 exactly
        const float na = attrs[sender * K_ATTR + k];
        const float s = rad * na;
        const int c = lane + 64 * it;              // chunk (4-f32 units)
        const size_t off = (size_t)c * 4;

        float4 pr, pi;
        pr.x = s * ysr[0]; pr.y = s * ysr[1]; pr.z = s * ysr[2]; pr.w = s * ysr[3];
        pi.x = s * ysi[0]; pi.y = s * ysi[1]; pi.z = s * ysi[2]; pi.w = s * ysi[3];
        *reinterpret_cast<float4*>(out + base_r + off) = pr;
        *reinterpret_cast<float4*>(out + base_i + off) = pi;
    }
}

extern "C" void kernel_launch(void* const* d_in, const int* in_sizes, int n_in,
                              void* d_out, int out_size, void* d_ws, size_t ws_size,
                              hipStream_t stream) {
    const int*   edge_index = (const int*)d_in[0];
    const float* lengths    = (const float*)d_in[1];
    const float* vecs       = (const float*)d_in[2];
    const float* attrs      = (const float*)d_in[3];
    float*       out        = (float*)d_out;

    const int blocks = E_CONST / 4;   // 4 waves/block, 1 wave/edge
    edge_embed_kernel<<<blocks, 256, 0, stream>>>(edge_index, lengths, vecs, attrs, out);
}